// Round 13
// baseline (347.344 us; speedup 1.0000x reference)
//
#include <hip/hip_runtime.h>
#include <hip/hip_fp16.h>

#define N_NODES 50000
#define N_EDGES 800000
#define CEILDIV(a,b) (((a)+(b)-1)/(b))
#define NB_SCAN CEILDIV(N_NODES, 256)   // 196 blocks

// ---------------------------------------------------------------------------
// CSR build (once per call, shared by all 3 layers)
// ---------------------------------------------------------------------------
__global__ __launch_bounds__(256) void k_deg_count(const int* __restrict__ dst,
                                                   int* __restrict__ degcnt, int e) {
    int i = blockIdx.x * 256 + threadIdx.x;
    if (i < e) atomicAdd(&degcnt[dst[i]], 1);
}

__global__ __launch_bounds__(256) void k_blocksum(const int* __restrict__ degcnt,
                                                  int* __restrict__ bsum, int n) {
    __shared__ int part[256];
    const int tid = threadIdx.x;
    const int gid = blockIdx.x * 256 + tid;
    part[tid] = (gid < n) ? degcnt[gid] : 0;
    __syncthreads();
    for (int off = 128; off > 0; off >>= 1) {
        if (tid < off) part[tid] += part[tid + off];
        __syncthreads();
    }
    if (tid == 0) bsum[blockIdx.x] = part[0];
}

__global__ __launch_bounds__(256) void k_scanb(const int* __restrict__ bsum,
                                               int* __restrict__ boff) {
    __shared__ int part[256];
    const int tid = threadIdx.x;
    part[tid] = (tid < NB_SCAN) ? bsum[tid] : 0;
    __syncthreads();
    for (int off = 1; off < 256; off <<= 1) {
        int v = (tid >= off) ? part[tid - off] : 0;
        __syncthreads();
        part[tid] += v;
        __syncthreads();
    }
    if (tid < NB_SCAN) boff[tid] = (tid == 0) ? 0 : part[tid - 1];
}

__global__ __launch_bounds__(256) void k_rowstart(const int* __restrict__ degcnt,
                                                  const int* __restrict__ boff,
                                                  int* __restrict__ rowstart,
                                                  float* __restrict__ dinv, int n) {
    __shared__ int part[256];
    const int tid = threadIdx.x;
    const int gid = blockIdx.x * 256 + tid;
    const int d = (gid < n) ? degcnt[gid] : 0;
    part[tid] = d;
    __syncthreads();
    for (int off = 1; off < 256; off <<= 1) {
        int v = (tid >= off) ? part[tid - off] : 0;
        __syncthreads();
        part[tid] += v;
        __syncthreads();
    }
    if (gid < n) {
        rowstart[gid] = boff[blockIdx.x] + part[tid] - d;   // exclusive
        dinv[gid] = rsqrtf((float)(d + 1));                 // +1 self loop
    }
    if (gid == 0) rowstart[n] = N_EDGES;
}

__global__ __launch_bounds__(256) void k_bin(const int* __restrict__ src,
                                             const int* __restrict__ dst,
                                             const int* __restrict__ rowstart,
                                             int* __restrict__ cursor,
                                             int* __restrict__ esrc, int e) {
    int i = blockIdx.x * 256 + threadIdx.x;
    if (i < e) {
        int d = dst[i];
        int pos = rowstart[d] + atomicAdd(&cursor[d], 1);
        esrc[pos] = src[i];
    }
}

// ---------------------------------------------------------------------------
// GEMM + row-scale + FP16 pack, TWO-PHASE W STAGING:
// W rows 0-63 in 32KB LDS -> first half of K-reduction; barrier; rows 64-127.
// Halved LDS -> 5 blocks/CU (was 2) -> enough waves to hide A-load latency.
// ---------------------------------------------------------------------------
template<int K, bool RELU>
__global__ __launch_bounds__(256, 5) void k_gemm(const float* __restrict__ A,
                                                 const float* __restrict__ W,
                                                 const float* __restrict__ dinv,
                                                 __half* __restrict__ C, int n) {
    constexpr int CG   = K / 4;            // 4-col groups (32 or 16)
    constexpr int RG   = 256 / CG;
    constexpr int ROWS = RG * 4;
    __shared__ float4 Wl4[64 * CG];        // half of W (rows 0-63 or 64-127)

    const int tid  = threadIdx.x;
    const int row0 = blockIdx.x * ROWS;

    const int cg = tid % CG;
    const int rg = tid / CG;
    const int gr = row0 + rg * 4;

    const float4* p0 = (const float4*)A + (size_t)min(gr + 0, n - 1) * 32;
    const float4* p1 = (const float4*)A + (size_t)min(gr + 1, n - 1) * 32;
    const float4* p2 = (const float4*)A + (size_t)min(gr + 2, n - 1) * 32;
    const float4* p3 = (const float4*)A + (size_t)min(gr + 3, n - 1) * 32;

    float4 acc0 = make_float4(0.f, 0.f, 0.f, 0.f);
    float4 acc1 = acc0, acc2 = acc0, acc3 = acc0;

    constexpr int WV = (64 * CG) / 256;    // float4s staged per thread per phase
    const float4* W4 = (const float4*)W;

    for (int ph = 0; ph < 2; ++ph) {
        if (ph) __syncthreads();           // all waves done with phase-0 W
#pragma unroll
        for (int i = 0; i < WV; ++i)
            Wl4[tid + i * 256] = W4[ph * 64 * CG + tid + i * 256];
        __syncthreads();

#pragma unroll 2
        for (int m4l = 0; m4l < 16; ++m4l) {
            const int m4 = ph * 16 + m4l;
            float4 a0 = p0[m4], a1 = p1[m4], a2 = p2[m4], a3 = p3[m4];
            if (RELU) {
                a0.x = fmaxf(a0.x, 0.f); a0.y = fmaxf(a0.y, 0.f); a0.z = fmaxf(a0.z, 0.f); a0.w = fmaxf(a0.w, 0.f);
                a1.x = fmaxf(a1.x, 0.f); a1.y = fmaxf(a1.y, 0.f); a1.z = fmaxf(a1.z, 0.f); a1.w = fmaxf(a1.w, 0.f);
                a2.x = fmaxf(a2.x, 0.f); a2.y = fmaxf(a2.y, 0.f); a2.z = fmaxf(a2.z, 0.f); a2.w = fmaxf(a2.w, 0.f);
                a3.x = fmaxf(a3.x, 0.f); a3.y = fmaxf(a3.y, 0.f); a3.z = fmaxf(a3.z, 0.f); a3.w = fmaxf(a3.w, 0.f);
            }
            const float4 w0 = Wl4[(m4l * 4 + 0) * CG + cg];
            const float4 w1 = Wl4[(m4l * 4 + 1) * CG + cg];
            const float4 w2 = Wl4[(m4l * 4 + 2) * CG + cg];
            const float4 w3 = Wl4[(m4l * 4 + 3) * CG + cg];

#define ROW_STEP(A_, ACC_)                                    \
            {                                                 \
                ACC_.x = fmaf(A_.x, w0.x, ACC_.x);            \
                ACC_.x = fmaf(A_.y, w1.x, ACC_.x);            \
                ACC_.x = fmaf(A_.z, w2.x, ACC_.x);            \
                ACC_.x = fmaf(A_.w, w3.x, ACC_.x);            \
                ACC_.y = fmaf(A_.x, w0.y, ACC_.y);            \
                ACC_.y = fmaf(A_.y, w1.y, ACC_.y);            \
                ACC_.y = fmaf(A_.z, w2.y, ACC_.y);            \
                ACC_.y = fmaf(A_.w, w3.y, ACC_.y);            \
                ACC_.z = fmaf(A_.x, w0.z, ACC_.z);            \
                ACC_.z = fmaf(A_.y, w1.z, ACC_.z);            \
                ACC_.z = fmaf(A_.z, w2.z, ACC_.z);            \
                ACC_.z = fmaf(A_.w, w3.z, ACC_.z);            \
                ACC_.w = fmaf(A_.x, w0.w, ACC_.w);            \
                ACC_.w = fmaf(A_.y, w1.w, ACC_.w);            \
                ACC_.w = fmaf(A_.z, w2.w, ACC_.w);            \
                ACC_.w = fmaf(A_.w, w3.w, ACC_.w);            \
            }
            ROW_STEP(a0, acc0);
            ROW_STEP(a1, acc1);
            ROW_STEP(a2, acc2);
            ROW_STEP(a3, acc3);
#undef ROW_STEP
        }
    }

    {
        float d0 = dinv[min(gr + 0, n - 1)];
        float d1 = dinv[min(gr + 1, n - 1)];
        float d2 = dinv[min(gr + 2, n - 1)];
        float d3 = dinv[min(gr + 3, n - 1)];
        union { __half2 h2[2]; uint2 u; } pk0, pk1, pk2, pk3;
        pk0.h2[0] = __floats2half2_rn(acc0.x * d0, acc0.y * d0);
        pk0.h2[1] = __floats2half2_rn(acc0.z * d0, acc0.w * d0);
        pk1.h2[0] = __floats2half2_rn(acc1.x * d1, acc1.y * d1);
        pk1.h2[1] = __floats2half2_rn(acc1.z * d1, acc1.w * d1);
        pk2.h2[0] = __floats2half2_rn(acc2.x * d2, acc2.y * d2);
        pk2.h2[1] = __floats2half2_rn(acc2.z * d2, acc2.w * d2);
        pk3.h2[0] = __floats2half2_rn(acc3.x * d3, acc3.y * d3);
        pk3.h2[1] = __floats2half2_rn(acc3.z * d3, acc3.w * d3);
        if (gr + 0 < n) ((uint2*)C)[(size_t)(gr + 0) * CG + cg] = pk0.u;
        if (gr + 1 < n) ((uint2*)C)[(size_t)(gr + 1) * CG + cg] = pk1.u;
        if (gr + 2 < n) ((uint2*)C)[(size_t)(gr + 2) * CG + cg] = pk2.u;
        if (gr + 3 < n) ((uint2*)C)[(size_t)(gr + 3) * CG + cg] = pk3.u;
    }
}

// ---------------------------------------------------------------------------
// Gather aggregation: fp16 h', one node per 32-lane group, 8-deep batch.
//   out[d][:] = dinv[d] * ( h'[d][:] + sum_{e: dst=d} h'[src_e][:] ) + b
// ---------------------------------------------------------------------------
template<int K>
__global__ __launch_bounds__(256) void k_aggregate(const __half* __restrict__ h,
                                                   const int* __restrict__ rowstart,
                                                   const int* __restrict__ esrc,
                                                   const float* __restrict__ dinv,
                                                   const float* __restrict__ b,
                                                   float* __restrict__ out, int n) {
    constexpr int VEC = K / 32;            // halves per lane (4 or 2)
    const int tid  = threadIdx.x;
    const int l5   = tid & 31;
    const int base = tid & 32;             // half-offset within the wave
    const int node = blockIdx.x * 8 + (tid >> 5);
    if (node >= n) return;

    float a0, a1, a2 = 0.f, a3 = 0.f;
    if (VEC == 4) {
        uint2 raw = ((const uint2*)h)[(size_t)node * 32 + l5];
        union { uint2 u; __half2 h2[2]; } c; c.u = raw;
        float2 lo = __half22float2(c.h2[0]);
        float2 hi = __half22float2(c.h2[1]);
        a0 = lo.x; a1 = lo.y; a2 = hi.x; a3 = hi.y;
    } else {
        uint raw = ((const uint*)h)[(size_t)node * 32 + l5];
        union { uint u; __half2 h2; } c; c.u = raw;
        float2 lo = __half22float2(c.h2);
        a0 = lo.x; a1 = lo.y;
    }

    int row = rowstart[node];
    const int end = rowstart[node + 1];

#define GATHER(SRC_, OK_)                                                     \
    if (VEC == 4) {                                                           \
        uint2 raw = make_uint2(0u, 0u);                                       \
        if (OK_) raw = ((const uint2*)h)[(size_t)(SRC_) * 32 + l5];           \
        union { uint2 u; __half2 h2[2]; } c; c.u = raw;                       \
        float2 lo = __half22float2(c.h2[0]);                                  \
        float2 hi = __half22float2(c.h2[1]);                                  \
        a0 += lo.x; a1 += lo.y; a2 += hi.x; a3 += hi.y;                       \
    } else {                                                                  \
        uint raw = 0u;                                                        \
        if (OK_) raw = ((const uint*)h)[(size_t)(SRC_) * 32 + l5];            \
        union { uint u; __half2 h2; } c; c.u = raw;                           \
        float2 lo = __half22float2(c.h2);                                     \
        a0 += lo.x; a1 += lo.y;                                               \
    }

    while (row < end) {
        int cnt = end - row;
        if (cnt > 32) cnt = 32;
        int s_l = (l5 < cnt) ? esrc[row + l5] : 0;
        for (int jj = 0; jj < cnt; jj += 8) {
            const int i0 = jj + 0, i1 = jj + 1, i2 = jj + 2, i3 = jj + 3;
            const int i4 = jj + 4, i5 = jj + 5, i6 = jj + 6, i7 = jj + 7;
            const int s0 = __shfl(s_l, base + i0);
            const int s1 = __shfl(s_l, base + i1);
            const int s2 = __shfl(s_l, base + i2);
            const int s3 = __shfl(s_l, base + i3);
            const int s4 = __shfl(s_l, base + i4);
            const int s5 = __shfl(s_l, base + i5);
            const int s6 = __shfl(s_l, base + i6);
            const int s7 = __shfl(s_l, base + i7);
            GATHER(s0, i0 < cnt);
            GATHER(s1, i1 < cnt);
            GATHER(s2, i2 < cnt);
            GATHER(s3, i3 < cnt);
            GATHER(s4, i4 < cnt);
            GATHER(s5, i5 < cnt);
            GATHER(s6, i6 < cnt);
            GATHER(s7, i7 < cnt);
        }
        row += cnt;
    }
#undef GATHER

    const float dd = dinv[node];
    if (VEC == 4) {
        float4 bb = ((const float4*)b)[l5];
        float4 o;
        o.x = a0 * dd + bb.x;
        o.y = a1 * dd + bb.y;
        o.z = a2 * dd + bb.z;
        o.w = a3 * dd + bb.w;
        ((float4*)out)[(size_t)node * 32 + l5] = o;
    } else {
        float2 bb = ((const float2*)b)[l5];
        float2 o;
        o.x = a0 * dd + bb.x;
        o.y = a1 * dd + bb.y;
        ((float2*)out)[(size_t)node * 32 + l5] = o;
    }
}

// ---------------------------------------------------------------------------
extern "C" void kernel_launch(void* const* d_in, const int* in_sizes, int n_in,
                              void* d_out, int out_size, void* d_ws, size_t ws_size,
                              hipStream_t stream) {
    const float* x  = (const float*)d_in[0];
    const int*   ei = (const int*)d_in[1];
    const float* W1 = (const float*)d_in[2];
    const float* b1 = (const float*)d_in[3];
    const float* W2 = (const float*)d_in[4];
    const float* b2 = (const float*)d_in[5];
    const float* W3 = (const float*)d_in[6];
    const float* b3 = (const float*)d_in[7];
    float* out = (float*)d_out;

    const int* src = ei;
    const int* dst = ei + N_EDGES;

    char* ws = (char*)d_ws;
    size_t off = 0;
    auto alloc = [&](size_t bytes) {
        void* p = ws + off;
        off += (bytes + 255) & ~(size_t)255;
        return p;
    };
    int*    degcnt   = (int*)alloc((size_t)N_NODES * 2 * 4);  // degcnt + cursor
    int*    cursor   = degcnt + N_NODES;
    int*    rowstart = (int*)alloc((N_NODES + 1) * 4);
    float*  dinv     = (float*)alloc(N_NODES * 4);
    int*    bsum     = (int*)alloc(NB_SCAN * 4);
    int*    boff     = (int*)alloc(NB_SCAN * 4);
    int*    esrc     = (int*)alloc((size_t)N_EDGES * 4);
    __half* hbuf     = (__half*)alloc((size_t)N_NODES * 128 * 2);  // fp16 h'
    float*  abuf     = (float*)alloc((size_t)N_NODES * 128 * 4);

    const int n = N_NODES, e = N_EDGES;

    // --- CSR build (once; reused by all layers) ---
    hipMemsetAsync(degcnt, 0, (size_t)N_NODES * 2 * 4, stream);
    k_deg_count<<<CEILDIV(e, 256), 256, 0, stream>>>(dst, degcnt, e);
    k_blocksum<<<NB_SCAN, 256, 0, stream>>>(degcnt, bsum, n);
    k_scanb<<<1, 256, 0, stream>>>(bsum, boff);
    k_rowstart<<<NB_SCAN, 256, 0, stream>>>(degcnt, boff, rowstart, dinv, n);
    k_bin<<<CEILDIV(e, 256), 256, 0, stream>>>(src, dst, rowstart, cursor, esrc, e);

    // --- layer 1 ---
    k_gemm<128, false><<<CEILDIV(n, 32), 256, 0, stream>>>(x, W1, dinv, hbuf, n);
    k_aggregate<128><<<CEILDIV(n, 8), 256, 0, stream>>>(hbuf, rowstart, esrc, dinv, b1, abuf, n);

    // --- layer 2 ---
    k_gemm<128, true><<<CEILDIV(n, 32), 256, 0, stream>>>(abuf, W2, dinv, hbuf, n);
    k_aggregate<128><<<CEILDIV(n, 8), 256, 0, stream>>>(hbuf, rowstart, esrc, dinv, b2, abuf, n);

    // --- layer 3 (K=64) ---
    k_gemm<64, true><<<CEILDIV(n, 64), 256, 0, stream>>>(abuf, W3, dinv, hbuf, n);
    k_aggregate<64><<<CEILDIV(n, 8), 256, 0, stream>>>(hbuf, rowstart, esrc, dinv, b3, out, n);
}

// Round 14
// 291.889 us; speedup vs baseline: 1.1900x; 1.1900x over previous
//
#include <hip/hip_runtime.h>
#include <hip/hip_fp16.h>

#define N_NODES 50000
#define N_EDGES 800000
#define CEILDIV(a,b) (((a)+(b)-1)/(b))
#define NB_SCAN CEILDIV(N_NODES, 256)   // 196 blocks

typedef _Float16 half8 __attribute__((ext_vector_type(8)));
typedef float    f32x4 __attribute__((ext_vector_type(4)));

// ---------------------------------------------------------------------------
// CSR build (once per call, shared by all 3 layers)
// ---------------------------------------------------------------------------
__global__ __launch_bounds__(256) void k_deg_count(const int* __restrict__ dst,
                                                   int* __restrict__ degcnt, int e) {
    int i = blockIdx.x * 256 + threadIdx.x;
    if (i < e) atomicAdd(&degcnt[dst[i]], 1);
}

__global__ __launch_bounds__(256) void k_blocksum(const int* __restrict__ degcnt,
                                                  int* __restrict__ bsum, int n) {
    __shared__ int part[256];
    const int tid = threadIdx.x;
    const int gid = blockIdx.x * 256 + tid;
    part[tid] = (gid < n) ? degcnt[gid] : 0;
    __syncthreads();
    for (int off = 128; off > 0; off >>= 1) {
        if (tid < off) part[tid] += part[tid + off];
        __syncthreads();
    }
    if (tid == 0) bsum[blockIdx.x] = part[0];
}

__global__ __launch_bounds__(256) void k_scanb(const int* __restrict__ bsum,
                                               int* __restrict__ boff) {
    __shared__ int part[256];
    const int tid = threadIdx.x;
    part[tid] = (tid < NB_SCAN) ? bsum[tid] : 0;
    __syncthreads();
    for (int off = 1; off < 256; off <<= 1) {
        int v = (tid >= off) ? part[tid - off] : 0;
        __syncthreads();
        part[tid] += v;
        __syncthreads();
    }
    if (tid < NB_SCAN) boff[tid] = (tid == 0) ? 0 : part[tid - 1];
}

__global__ __launch_bounds__(256) void k_rowstart(const int* __restrict__ degcnt,
                                                  const int* __restrict__ boff,
                                                  int* __restrict__ rowstart,
                                                  float* __restrict__ dinv, int n) {
    __shared__ int part[256];
    const int tid = threadIdx.x;
    const int gid = blockIdx.x * 256 + tid;
    const int d = (gid < n) ? degcnt[gid] : 0;
    part[tid] = d;
    __syncthreads();
    for (int off = 1; off < 256; off <<= 1) {
        int v = (tid >= off) ? part[tid - off] : 0;
        __syncthreads();
        part[tid] += v;
        __syncthreads();
    }
    if (gid < n) {
        rowstart[gid] = boff[blockIdx.x] + part[tid] - d;   // exclusive
        dinv[gid] = rsqrtf((float)(d + 1));                 // +1 self loop
    }
    if (gid == 0) rowstart[n] = N_EDGES;
}

__global__ __launch_bounds__(256) void k_bin(const int* __restrict__ src,
                                             const int* __restrict__ dst,
                                             const int* __restrict__ rowstart,
                                             int* __restrict__ cursor,
                                             int* __restrict__ esrc, int e) {
    int i = blockIdx.x * 256 + threadIdx.x;
    if (i < e) {
        int d = dst[i];
        int pos = rowstart[d] + atomicAdd(&cursor[d], 1);
        esrc[pos] = src[i];
    }
}

// ---------------------------------------------------------------------------
// one-time casts: x (f32) -> fp16 rows; W (f32 [128][K]) -> W^T fp16 [K][128]
// ---------------------------------------------------------------------------
__global__ __launch_bounds__(256) void k_x2h(const float* __restrict__ x,
                                             __half* __restrict__ xh, long total) {
    long i = (long)(blockIdx.x * 256 + threadIdx.x) * 8;
    if (i >= total) return;
    float4 lo = ((const float4*)x)[i / 4];
    float4 hi = ((const float4*)x)[i / 4 + 1];
    union { __half2 h2[4]; uint4 u; } pk;
    pk.h2[0] = __floats2half2_rn(lo.x, lo.y);
    pk.h2[1] = __floats2half2_rn(lo.z, lo.w);
    pk.h2[2] = __floats2half2_rn(hi.x, hi.y);
    pk.h2[3] = __floats2half2_rn(hi.z, hi.w);
    ((uint4*)xh)[i / 8] = pk.u;
}

template<int KOUT>
__global__ __launch_bounds__(256) void k_w2h(const float* __restrict__ W,
                                             __half* __restrict__ Wt) {
    int idx = blockIdx.x * 256 + threadIdx.x;   // idx over KOUT*128
    if (idx >= KOUT * 128) return;
    int c = idx >> 7;          // out column (W^T row)
    int k = idx & 127;         // inner index
    Wt[c * 128 + k] = __float2half(W[(size_t)k * KOUT + c]);
}

// ---------------------------------------------------------------------------
// MFMA GEMM: C[i][:] = fp16( (RELU? relu(A):A)[i][0..127] @ W  * dinv[i] )
// A fp16 [n][128]; Wt = W^T fp16 [KOUT][128]. Block: 256 thr = 4 waves,
// BM=64 (16 rows/wave), all KOUT cols per wave. LDS XOR-swizzle (row&7)<<4
// makes frag ds_read_b128 2-way (free). mfma_f32_16x16x32_f16:
// D[col=lane&15, row=(lane>>4)*4+reg]; A row=lane&15, k=8*(lane>>4)+j.
// ---------------------------------------------------------------------------
template<int KOUT, bool RELU>
__global__ __launch_bounds__(256) void k_gemm(const __half* __restrict__ A,
                                              const __half* __restrict__ Wt,
                                              const float* __restrict__ dinv,
                                              __half* __restrict__ C, int n) {
    constexpr int NT     = KOUT / 16;        // col tiles per wave (8 or 4)
    constexpr int ABYTES = 64 * 256;         // 64 rows x 128 fp16
    constexpr int WBYTES = KOUT * 256;       // KOUT rows x 128 fp16
    __shared__ uint4 ldsbuf[(ABYTES + WBYTES) / 16];
    char* Als = (char*)ldsbuf;
    char* Wls = Als + ABYTES;

    const int tid  = threadIdx.x;
    const int row0 = blockIdx.x * 64;

    // ---- stage A tile (64 rows x 256B), fused ReLU, swizzled ----
#pragma unroll
    for (int i = 0; i < 4; ++i) {            // 1024 chunks of 16B
        int g   = tid + i * 256;
        int r   = g >> 4;                    // local row
        int ch  = g & 15;                    // 16B chunk in row
        int gr  = row0 + r;
        uint4 v = make_uint4(0u, 0u, 0u, 0u);
        if (gr < n) v = ((const uint4*)A)[(size_t)gr * 16 + ch];
        if (RELU) {
            uint n0 = (v.x >> 15) & 0x00010001u; v.x &= ~(n0 * 0xFFFFu);
            uint n1 = (v.y >> 15) & 0x00010001u; v.y &= ~(n1 * 0xFFFFu);
            uint n2 = (v.z >> 15) & 0x00010001u; v.z &= ~(n2 * 0xFFFFu);
            uint n3 = (v.w >> 15) & 0x00010001u; v.w &= ~(n3 * 0xFFFFu);
        }
        *(uint4*)(Als + r * 256 + ((ch * 16) ^ ((r & 7) << 4))) = v;
    }
    // ---- stage W^T (KOUT rows x 256B), swizzled ----
#pragma unroll
    for (int i = 0; i < WBYTES / 16 / 256; ++i) {
        int g  = tid + i * 256;
        int r  = g >> 4;
        int ch = g & 15;
        uint4 v = ((const uint4*)Wt)[(size_t)r * 16 + ch];
        *(uint4*)(Wls + r * 256 + ((ch * 16) ^ ((r & 7) << 4))) = v;
    }
    __syncthreads();

    const int wave = tid >> 6;
    const int lane = tid & 63;
    const int l15  = lane & 15;
    const int l4   = lane >> 4;

    f32x4 acc[NT];
#pragma unroll
    for (int ct = 0; ct < NT; ++ct) acc[ct] = (f32x4){0.f, 0.f, 0.f, 0.f};

#pragma unroll
    for (int kb = 0; kb < 4; ++kb) {
        const int arow = 16 * wave + l15;
        half8 af = *(half8*)(Als + arow * 256 +
                             (((kb * 64) + l4 * 16) ^ ((arow & 7) << 4)));
#pragma unroll
        for (int ct = 0; ct < NT; ++ct) {
            const int wrow = ct * 16 + l15;
            half8 bf = *(half8*)(Wls + wrow * 256 +
                                 (((kb * 64) + l4 * 16) ^ ((wrow & 7) << 4)));
            acc[ct] = __builtin_amdgcn_mfma_f32_16x16x32_f16(af, bf, acc[ct], 0, 0, 0);
        }
    }

    // ---- epilogue: dinv-scale, fp16, scattered 2B stores ----
    const int rbase = row0 + 16 * wave + l4 * 4;
    const float d0 = dinv[min(rbase + 0, n - 1)];
    const float d1 = dinv[min(rbase + 1, n - 1)];
    const float d2 = dinv[min(rbase + 2, n - 1)];
    const float d3 = dinv[min(rbase + 3, n - 1)];
#pragma unroll
    for (int ct = 0; ct < NT; ++ct) {
        const int col = ct * 16 + l15;
        if (rbase + 0 < n) C[(size_t)(rbase + 0) * KOUT + col] = __float2half(acc[ct][0] * d0);
        if (rbase + 1 < n) C[(size_t)(rbase + 1) * KOUT + col] = __float2half(acc[ct][1] * d1);
        if (rbase + 2 < n) C[(size_t)(rbase + 2) * KOUT + col] = __float2half(acc[ct][2] * d2);
        if (rbase + 3 < n) C[(size_t)(rbase + 3) * KOUT + col] = __float2half(acc[ct][3] * d3);
    }
}

// ---------------------------------------------------------------------------
// Gather aggregation: fp16 h', one node per 32-lane group, 8-deep batch.
//   out[d][:] = dinv[d] * ( h'[d][:] + sum_{e: dst=d} h'[src_e][:] ) + b
// HOUT: write fp16 (feeds next MFMA gemm); else f32 (final output).
// ---------------------------------------------------------------------------
template<int K, bool HOUT>
__global__ __launch_bounds__(256) void k_aggregate(const __half* __restrict__ h,
                                                   const int* __restrict__ rowstart,
                                                   const int* __restrict__ esrc,
                                                   const float* __restrict__ dinv,
                                                   const float* __restrict__ b,
                                                   void* __restrict__ out, int n) {
    constexpr int VEC = K / 32;            // halves per lane (4 or 2)
    const int tid  = threadIdx.x;
    const int l5   = tid & 31;
    const int base = tid & 32;
    const int node = blockIdx.x * 8 + (tid >> 5);
    if (node >= n) return;

    float a0, a1, a2 = 0.f, a3 = 0.f;
    if (VEC == 4) {
        uint2 raw = ((const uint2*)h)[(size_t)node * 32 + l5];
        union { uint2 u; __half2 h2[2]; } c; c.u = raw;
        float2 lo = __half22float2(c.h2[0]);
        float2 hi = __half22float2(c.h2[1]);
        a0 = lo.x; a1 = lo.y; a2 = hi.x; a3 = hi.y;
    } else {
        uint raw = ((const uint*)h)[(size_t)node * 32 + l5];
        union { uint u; __half2 h2; } c; c.u = raw;
        float2 lo = __half22float2(c.h2);
        a0 = lo.x; a1 = lo.y;
    }

    int row = rowstart[node];
    const int end = rowstart[node + 1];

#define GATHER(SRC_, OK_)                                                     \
    if (VEC == 4) {                                                           \
        uint2 raw = make_uint2(0u, 0u);                                       \
        if (OK_) raw = ((const uint2*)h)[(size_t)(SRC_) * 32 + l5];           \
        union { uint2 u; __half2 h2[2]; } c; c.u = raw;                       \
        float2 lo = __half22float2(c.h2[0]);                                  \
        float2 hi = __half22float2(c.h2[1]);                                  \
        a0 += lo.x; a1 += lo.y; a2 += hi.x; a3 += hi.y;                       \
    } else {                                                                  \
        uint raw = 0u;                                                        \
        if (OK_) raw = ((const uint*)h)[(size_t)(SRC_) * 32 + l5];            \
        union { uint u; __half2 h2; } c; c.u = raw;                           \
        float2 lo = __half22float2(c.h2);                                     \
        a0 += lo.x; a1 += lo.y;                                               \
    }

    while (row < end) {
        int cnt = end - row;
        if (cnt > 32) cnt = 32;
        int s_l = (l5 < cnt) ? esrc[row + l5] : 0;
        for (int jj = 0; jj < cnt; jj += 8) {
            const int i0 = jj + 0, i1 = jj + 1, i2 = jj + 2, i3 = jj + 3;
            const int i4 = jj + 4, i5 = jj + 5, i6 = jj + 6, i7 = jj + 7;
            const int s0 = __shfl(s_l, base + i0);
            const int s1 = __shfl(s_l, base + i1);
            const int s2 = __shfl(s_l, base + i2);
            const int s3 = __shfl(s_l, base + i3);
            const int s4 = __shfl(s_l, base + i4);
            const int s5 = __shfl(s_l, base + i5);
            const int s6 = __shfl(s_l, base + i6);
            const int s7 = __shfl(s_l, base + i7);
            GATHER(s0, i0 < cnt);
            GATHER(s1, i1 < cnt);
            GATHER(s2, i2 < cnt);
            GATHER(s3, i3 < cnt);
            GATHER(s4, i4 < cnt);
            GATHER(s5, i5 < cnt);
            GATHER(s6, i6 < cnt);
            GATHER(s7, i7 < cnt);
        }
        row += cnt;
    }
#undef GATHER

    const float dd = dinv[node];
    if (VEC == 4) {
        float4 bb = ((const float4*)b)[l5];
        float o0 = a0 * dd + bb.x, o1 = a1 * dd + bb.y;
        float o2 = a2 * dd + bb.z, o3 = a3 * dd + bb.w;
        if (HOUT) {
            union { __half2 h2[2]; uint2 u; } pk;
            pk.h2[0] = __floats2half2_rn(o0, o1);
            pk.h2[1] = __floats2half2_rn(o2, o3);
            ((uint2*)out)[(size_t)node * 32 + l5] = pk.u;
        } else {
            ((float4*)out)[(size_t)node * 32 + l5] = make_float4(o0, o1, o2, o3);
        }
    } else {
        float2 bb = ((const float2*)b)[l5];
        float o0 = a0 * dd + bb.x, o1 = a1 * dd + bb.y;
        if (HOUT) {
            union { __half2 h2; uint u; } pk;
            pk.h2 = __floats2half2_rn(o0, o1);
            ((uint*)out)[(size_t)node * 32 + l5] = pk.u;
        } else {
            ((float2*)out)[(size_t)node * 32 + l5] = make_float2(o0, o1);
        }
    }
}

// ---------------------------------------------------------------------------
extern "C" void kernel_launch(void* const* d_in, const int* in_sizes, int n_in,
                              void* d_out, int out_size, void* d_ws, size_t ws_size,
                              hipStream_t stream) {
    const float* x  = (const float*)d_in[0];
    const int*   ei = (const int*)d_in[1];
    const float* W1 = (const float*)d_in[2];
    const float* b1 = (const float*)d_in[3];
    const float* W2 = (const float*)d_in[4];
    const float* b2 = (const float*)d_in[5];
    const float* W3 = (const float*)d_in[6];
    const float* b3 = (const float*)d_in[7];
    float* out = (float*)d_out;

    const int* src = ei;
    const int* dst = ei + N_EDGES;

    char* ws = (char*)d_ws;
    size_t off = 0;
    auto alloc = [&](size_t bytes) {
        void* p = ws + off;
        off += (bytes + 255) & ~(size_t)255;
        return p;
    };
    int*    degcnt   = (int*)alloc((size_t)N_NODES * 2 * 4);  // degcnt + cursor
    int*    cursor   = degcnt + N_NODES;
    int*    rowstart = (int*)alloc((N_NODES + 1) * 4);
    float*  dinv     = (float*)alloc(N_NODES * 4);
    int*    bsum     = (int*)alloc(NB_SCAN * 4);
    int*    boff     = (int*)alloc(NB_SCAN * 4);
    int*    esrc     = (int*)alloc((size_t)N_EDGES * 4);
    __half* xh       = (__half*)alloc((size_t)N_NODES * 128 * 2);
    __half* hbuf     = (__half*)alloc((size_t)N_NODES * 128 * 2);  // h' fp16
    __half* abuf     = (__half*)alloc((size_t)N_NODES * 128 * 2);  // activations fp16
    __half* wt1      = (__half*)alloc(128 * 128 * 2);
    __half* wt2      = (__half*)alloc(128 * 128 * 2);
    __half* wt3      = (__half*)alloc(64 * 128 * 2);

    const int n = N_NODES, e = N_EDGES;

    // --- CSR build (once; reused by all layers) ---
    hipMemsetAsync(degcnt, 0, (size_t)N_NODES * 2 * 4, stream);
    k_deg_count<<<CEILDIV(e, 256), 256, 0, stream>>>(dst, degcnt, e);
    k_blocksum<<<NB_SCAN, 256, 0, stream>>>(degcnt, bsum, n);
    k_scanb<<<1, 256, 0, stream>>>(bsum, boff);
    k_rowstart<<<NB_SCAN, 256, 0, stream>>>(degcnt, boff, rowstart, dinv, n);
    k_bin<<<CEILDIV(e, 256), 256, 0, stream>>>(src, dst, rowstart, cursor, esrc, e);

    // --- one-time fp16 casts ---
    k_x2h<<<CEILDIV((long)n * 128, 8 * 256), 256, 0, stream>>>(x, xh, (long)n * 128);
    k_w2h<128><<<CEILDIV(128 * 128, 256), 256, 0, stream>>>(W1, wt1);
    k_w2h<128><<<CEILDIV(128 * 128, 256), 256, 0, stream>>>(W2, wt2);
    k_w2h<64><<<CEILDIV(64 * 128, 256), 256, 0, stream>>>(W3, wt3);

    // --- layer 1 ---
    k_gemm<128, false><<<CEILDIV(n, 64), 256, 0, stream>>>(xh, wt1, dinv, hbuf, n);
    k_aggregate<128, true><<<CEILDIV(n, 8), 256, 0, stream>>>(hbuf, rowstart, esrc, dinv, b1, abuf, n);

    // --- layer 2 ---
    k_gemm<128, true><<<CEILDIV(n, 64), 256, 0, stream>>>(abuf, wt2, dinv, hbuf, n);
    k_aggregate<128, true><<<CEILDIV(n, 8), 256, 0, stream>>>(hbuf, rowstart, esrc, dinv, b2, abuf, n);

    // --- layer 3 (K=64) ---
    k_gemm<64, true><<<CEILDIV(n, 64), 256, 0, stream>>>(abuf, wt3, dinv, hbuf, n);
    k_aggregate<64, false><<<CEILDIV(n, 8), 256, 0, stream>>>(hbuf, rowstart, esrc, dinv, b3, out, n);
}